// Round 7
// baseline (186.147 us; speedup 1.0000x reference)
//
#include <hip/hip_runtime.h>
#include <cmath>

typedef unsigned int uint;

constexpr int N  = 131072;    // nodes
constexpr int E  = 4194304;   // edges (without self-loops)
constexpr int F  = 16;        // hidden width H1
constexpr int NB = 512;       // dst buckets of 256 nodes (bucket = dst>>8)
constexpr int NBLK  = 512;    // scatter blocks
constexpr int SCT   = 512;    // threads per scatter block
constexpr int GT    = 1024;   // threads per gather block (16 waves)
constexpr int CHUNK = 8192;   // edges per scatter block (NBLK*CHUNK == E)
constexpr int EPT   = 16;     // edges per thread in scatter
constexpr int CAPB  = 9216;   // per-bucket region (mean 8192, sd ~90 -> 11 sigma)
constexpr int LT    = 1024;   // threads per l1/l2 block (16 waves)

// ---- Pass 1: block-local bucket grouping, coalesced part write -------------
__global__ void __launch_bounds__(SCT) k_scatter(
        const int* __restrict__ src, const int* __restrict__ dst,
        uint* __restrict__ part, uint* __restrict__ dirw) {
    __shared__ uint h[NB];          // hist -> bump counters
    __shared__ uint wsum[8];
    __shared__ uint vals[CHUNK];    // 32 KB staging
    int t = threadIdx.x, g = blockIdx.x;
    int lane = t & 63, w = t >> 6;
    h[t] = 0;
    __syncthreads();
    int d[EPT], s[EPT];
    const int4* src4 = (const int4*)src;
    const int4* dst4 = (const int4*)dst;
    int base4 = g * (CHUNK / 4);
#pragma unroll
    for (int k = 0; k < EPT / 4; ++k) {
        int4 d4 = dst4[base4 + k * SCT + t];
        int4 s4 = src4[base4 + k * SCT + t];
        d[4 * k + 0] = d4.x; d[4 * k + 1] = d4.y; d[4 * k + 2] = d4.z; d[4 * k + 3] = d4.w;
        s[4 * k + 0] = s4.x; s[4 * k + 1] = s4.y; s[4 * k + 2] = s4.z; s[4 * k + 3] = s4.w;
        atomicAdd(&h[d4.x >> 8], 1u);
        atomicAdd(&h[d4.y >> 8], 1u);
        atomicAdd(&h[d4.z >> 8], 1u);
        atomicAdd(&h[d4.w >> 8], 1u);
    }
    __syncthreads();
    uint v = h[t];
    uint sv = v;                                  // wave inclusive scan
#pragma unroll
    for (int off = 1; off < 64; off <<= 1) {
        uint n = __shfl_up(sv, off);
        if (lane >= off) sv += n;
    }
    if (lane == 63) wsum[w] = sv;
    __syncthreads();
    uint wo = 0;
    for (int i = 0; i < w; ++i) wo += wsum[i];
    sv += wo;                                     // inclusive over 512 buckets
    uint ex = sv - v;                             // local exclusive offset
    dirw[(size_t)g * NB + t] = v | (ex << 16);    // coalesced directory store
    __syncthreads();                              // all reads of h done
    h[t] = ex;                                    // bump starts at excl
    __syncthreads();
#pragma unroll
    for (int k = 0; k < EPT; ++k) {
        int b = d[k] >> 8;
        uint slot = atomicAdd(&h[b], 1u);
        vals[slot] = ((uint)s[k] << 8) | (uint)(d[k] & 255);
    }
    __syncthreads();
    uint4* part4 = (uint4*)(part + (size_t)g * CHUNK);
    const uint4* vals4 = (const uint4*)vals;
#pragma unroll
    for (int k = 0; k < EPT / 4; ++k)             // fully coalesced 16B stores
        part4[k * SCT + t] = vals4[k * SCT + t];
}

// ---- Pass 2: run-walk gather + block-local COUNTING SORT by dst node -------
// part2[bucket] comes out sorted by destination node: per-wave per-node
// histogram (hw) -> exclusive prefix over waves and nodes -> collision-free
// per-wave placement bases -> one LDS-bump placement sweep. Downstream l1/l2
// then need NO atomics at all (contiguous per-node segments).
__global__ void __launch_bounds__(GT) k_gather(
        const uint* __restrict__ part, const uint* __restrict__ dirw,
        const float* __restrict__ x,
        uint* __restrict__ part2, uint* __restrict__ nstart,
        uint* __restrict__ degg, float* __restrict__ dinv, float2* __restrict__ y) {
    __shared__ uint ps[NB + 1];     // exclusive prefix of run lengths
    __shared__ uint segoff[NB];     // global offset of each run in part
    __shared__ uint hw[16 * 256];   // per-wave per-node counts -> bump bases
    __shared__ uint stage[CAPB];    // 36 KB edge staging
    __shared__ uint wsum[8];
    int t = threadIdx.x, b = blockIdx.x;
    int lane = t & 63, w = t >> 6;
#pragma unroll
    for (int k = 0; k < 4; ++k) hw[k * GT + t] = 0;
    if (t < NB) {
        uint pd = dirw[(size_t)t * NB + b];       // column read (L2-hot)
        uint len = pd & 0xFFFFu;
        segoff[t] = (uint)t * CHUNK + (pd >> 16);
        uint sv = len;
#pragma unroll
        for (int off = 1; off < 64; off <<= 1) {
            uint n = __shfl_up(sv, off);
            if (lane >= off) sv += n;
        }
        if (lane == 63) wsum[w] = sv;
        ps[t] = sv - len;                         // partial (pre cross-wave)
    }
    __syncthreads();
    if (t < NB) {
        uint wo = 0;
        for (int i = 0; i < w; ++i) wo += wsum[i];
        ps[t] += wo;
    }
    if (t == 0) {
        uint Lt = 0;
#pragma unroll
        for (int i = 0; i < 8; ++i) Lt += wsum[i];
        ps[NB] = Lt;
    }
    __syncthreads();
    int sub = lane >> 4, l16 = lane & 15;         // 4 runs per wave
    // sweep A: stage edges + wave-private per-node count
#pragma unroll
    for (int pass = 0; pass < 8; ++pass) {        // 16 waves * 4 * 8 = 512 runs
        int r = pass * 64 + w * 4 + sub;
        uint off = segoff[r], base = ps[r], len = ps[r + 1] - base;
        for (uint j = l16; j < len; j += 16) {
            uint pk = part[off + j];
            atomicAdd(&hw[w * 256 + (pk & 255u)], 1u);
            if (base + j < (uint)CAPB) stage[base + j] = pk;
        }
    }
    __syncthreads();
    uint degc = 0, svn = 0;
    if (t < 256) {                                // t indexes node-in-bucket
        uint c = 0;                               // hw: count -> excl prefix/wave
#pragma unroll
        for (int k = 0; k < 16; ++k) {
            uint v0 = hw[k * 256 + t];
            hw[k * 256 + t] = c;
            c += v0;
        }
        degc = c;
        svn = c;                                  // 256-node scan (4 waves)
#pragma unroll
        for (int off = 1; off < 64; off <<= 1) {
            uint n2 = __shfl_up(svn, off);
            if (lane >= off) svn += n2;
        }
        if (lane == 63) wsum[w] = svn;            // w in 0..3 here
    }
    __syncthreads();
    if (t < 256) {
        uint wo = 0;
        for (int i = 0; i < w; ++i) wo += wsum[i];
        uint ex = svn - degc + wo;                // node start within bucket
#pragma unroll
        for (int k = 0; k < 16; ++k) hw[k * 256 + t] += ex;   // absolute bases
        int node = (b << 8) + t;
        nstart[node] = ex;
        degg[node]   = degc;
        float di = rsqrtf(1.0f + (float)degc);    // +1 self-loop
        dinv[node] = di;
        float2 xv = ((const float2*)x)[node];
        y[node] = make_float2(di * xv.x, di * xv.y);
    }
    __syncthreads();
    // sweep B: place (wave-private bump -> no cross-wave contention)
    uint* o2 = part2 + (size_t)b * CAPB;
#pragma unroll
    for (int pass = 0; pass < 8; ++pass) {
        int r = pass * 64 + w * 4 + sub;
        uint base = ps[r], len = ps[r + 1] - base;
        for (uint j = l16; j < len; j += 16) {
            if (base + j < (uint)CAPB) {
                uint pk = stage[base + j];
                uint pos = atomicAdd(&hw[w * 256 + (pk & 255u)], 1u);
                if (pos < (uint)CAPB) o2[pos] = pk >> 8;     // store src only
            }
        }
    }
}

// ---- Pass 3: layer 1 — atomic-free segmented reduce + 16-wide MLP ----------
// One 16-lane group per node; 4 consecutive nodes per wave -> contiguous
// part2 window. f32 register accumulation, shfl-tree reduce, MLP computed
// 16-wide (feature f = lane) then reduced.
__global__ void __launch_bounds__(LT) k_l1(
        const uint* __restrict__ part2, const uint* __restrict__ nstart,
        const uint* __restrict__ degg,
        const float2* __restrict__ y, const float* __restrict__ dinv,
        const float* __restrict__ W1, const float* __restrict__ b1,
        const float* __restrict__ W2, float* __restrict__ g2) {
    int t = threadIdx.x, b = blockIdx.x;
    int grp = t >> 4, l16 = t & 15;               // 64 groups of 16 lanes
    float w1a = W1[l16], w1b = W1[F + l16], bb = b1[l16], w2 = W2[l16];
    const uint* p2 = part2 + (size_t)b * CAPB;
#pragma unroll
    for (int idx = 0; idx < 4; ++idx) {
        int n = idx * 64 + grp;
        int node = (b << 8) + n;
        uint s = nstart[node], d = degg[node];
        float a0 = 0.0f, a1 = 0.0f;
        for (uint j = l16; j < d; j += 16) {
            float2 yv = y[p2[s + j]];             // random gather, L2-resident
            a0 += yv.x; a1 += yv.y;
        }
#pragma unroll
        for (int off = 8; off >= 1; off >>= 1) {
            a0 += __shfl_down(a0, off, 16);
            a1 += __shfl_down(a1, off, 16);
        }
        a0 = __shfl(a0, 0, 16);                   // broadcast sums
        a1 = __shfl(a1, 0, 16);
        float di = dinv[node];
        float2 yn = y[node];
        float A0 = di * (a0 + yn.x);              // + self-loop
        float A1 = di * (a1 + yn.y);
        float v = fmaf(A0, w1a, fmaf(A1, w1b, bb));
        float r = fmaxf(v, 0.0f) * w2;            // feature l16's contribution
#pragma unroll
        for (int off = 8; off >= 1; off >>= 1) r += __shfl_down(r, off, 16);
        if (l16 == 0) g2[node] = di * r;
    }
}

// ---- Pass 4: layer 2 — atomic-free segmented reduce + sigmoid --------------
__global__ void __launch_bounds__(LT) k_l2(
        const uint* __restrict__ part2, const uint* __restrict__ nstart,
        const uint* __restrict__ degg,
        const float* __restrict__ g2, const float* __restrict__ dinv,
        const float* __restrict__ b2, float* __restrict__ scores) {
    int t = threadIdx.x, b = blockIdx.x;
    int grp = t >> 4, l16 = t & 15;
    float bb = b2[0];
    const uint* p2 = part2 + (size_t)b * CAPB;
#pragma unroll
    for (int idx = 0; idx < 4; ++idx) {
        int n = idx * 64 + grp;
        int node = (b << 8) + n;
        uint s = nstart[node], d = degg[node];
        float a = 0.0f;
        for (uint j = l16; j < d; j += 16) a += g2[p2[s + j]];
#pragma unroll
        for (int off = 8; off >= 1; off >>= 1) a += __shfl_down(a, off, 16);
        if (l16 == 0) {
            float v = fmaf(dinv[node], a + g2[node], bb);
            scores[node] = 1.0f / (1.0f + expf(-v));
        }
    }
}

// ---- output gather: out[e] = scores[src[e]], 8 edges/thread (TA ILP) -------
__global__ void k_out(const int* __restrict__ src, const float* __restrict__ scores,
                      float* __restrict__ out) {
    int i = blockIdx.x * blockDim.x + threadIdx.x;
    if (i >= E / 8) return;
    const int4* s4p = (const int4*)src;
    int4 sa = s4p[2 * i], sb = s4p[2 * i + 1];
    float4 oa, ob;                                // 8 independent gathers in flight
    oa.x = scores[sa.x];
    oa.y = scores[sa.y];
    oa.z = scores[sa.z];
    oa.w = scores[sa.w];
    ob.x = scores[sb.x];
    ob.y = scores[sb.y];
    ob.z = scores[sb.z];
    ob.w = scores[sb.w];
    ((float4*)out)[2 * i]     = oa;
    ((float4*)out)[2 * i + 1] = ob;
}

extern "C" void kernel_launch(void* const* d_in, const int* in_sizes, int n_in,
                              void* d_out, int out_size, void* d_ws, size_t ws_size,
                              hipStream_t stream) {
    const float* x  = (const float*)d_in[0];   // [N,2]
    const float* W1 = (const float*)d_in[1];   // [2,16]
    const float* b1 = (const float*)d_in[2];   // [16]
    const float* W2 = (const float*)d_in[3];   // [16,1]
    const float* b2 = (const float*)d_in[4];   // [1]
    const int*   ei = (const int*)d_in[5];     // [2,E]
    const int* src = ei;
    const int* dst = ei + E;

    // ws: dirw[512*512 u32] | nstart[N] | deg[N] | dinv[N] | y[N f32x2] |
    //     g2[N] | scores[N] | part2[NB*CAPB u32]   (~23.5 MB)
    uint*   dirw   = (uint*)d_ws;
    uint*   nstart = dirw + (size_t)NB * NB;
    uint*   degg   = nstart + N;
    float*  dinv   = (float*)(degg + N);
    float2* y      = (float2*)(dinv + N);
    float*  g2     = (float*)(y + N);
    float*  scores = g2 + N;
    uint*   part2  = (uint*)(scores + N);

    // block-grouped edges (16 MB) live in d_out; dead before k_out writes
    uint* part  = (uint*)d_out;
    float* out  = (float*)d_out;

    k_scatter<<<NBLK,        SCT, 0, stream>>>(src, dst, part, dirw);
    k_gather <<<NB,          GT,  0, stream>>>(part, dirw, x, part2, nstart,
                                               degg, dinv, y);
    k_l1     <<<NB,          LT,  0, stream>>>(part2, nstart, degg, y, dinv,
                                               W1, b1, W2, g2);
    k_l2     <<<NB,          LT,  0, stream>>>(part2, nstart, degg, g2, dinv,
                                               b2, scores);
    k_out    <<<E / 8 / 256, 256, 0, stream>>>(src, scores, out);
}

// Round 8
// 164.619 us; speedup vs baseline: 1.1308x; 1.1308x over previous
//
#include <hip/hip_runtime.h>
#include <cmath>

typedef unsigned int uint;

constexpr int N  = 131072;    // nodes
constexpr int E  = 4194304;   // edges (without self-loops)
constexpr int F  = 16;        // hidden width H1
constexpr int NB = 512;       // dst buckets of 256 nodes (bucket = dst>>8)
constexpr int NBLK  = 512;    // scatter blocks
constexpr int SCT   = 512;    // threads per scatter block
constexpr int GT    = 1024;   // threads per gather block (16 waves)
constexpr int CHUNK = 8192;   // edges per scatter block (NBLK*CHUNK == E)
constexpr int EPT   = 16;     // edges per thread in scatter
constexpr int CAPB  = 9216;   // padded per-bucket region (mean 8192, sd ~90; %4==0)
constexpr int LT    = 1024;   // threads per l1/l2 block (16 waves)
constexpr uint SENT = 0xFFFFFFFFu;   // pad sentinel edge

// Fixed-point scales for native int LDS atomics (float LDS atomicAdd is a
// CAS loop on gfx9; int ds_add is native — verified in the earlier session).
constexpr float S1 = 4194304.0f;    // 2^22 for layer-1 sums (|y|<1, deg<=~64)
constexpr float S2 = 65536.0f;      // 2^16 for layer-2 sums (|g2| small)

// ---- Pass 1: block-local bucket grouping, coalesced part write -------------
__global__ void __launch_bounds__(SCT) k_scatter(
        const int* __restrict__ src, const int* __restrict__ dst,
        uint* __restrict__ part, uint* __restrict__ dirw) {
    __shared__ uint h[NB];          // hist -> bump counters
    __shared__ uint wsum[8];
    __shared__ uint vals[CHUNK];    // 32 KB staging
    int t = threadIdx.x, g = blockIdx.x;
    int lane = t & 63, w = t >> 6;
    h[t] = 0;
    __syncthreads();
    int d[EPT], s[EPT];
    const int4* src4 = (const int4*)src;
    const int4* dst4 = (const int4*)dst;
    int base4 = g * (CHUNK / 4);
#pragma unroll
    for (int k = 0; k < EPT / 4; ++k) {
        int4 d4 = dst4[base4 + k * SCT + t];
        int4 s4 = src4[base4 + k * SCT + t];
        d[4 * k + 0] = d4.x; d[4 * k + 1] = d4.y; d[4 * k + 2] = d4.z; d[4 * k + 3] = d4.w;
        s[4 * k + 0] = s4.x; s[4 * k + 1] = s4.y; s[4 * k + 2] = s4.z; s[4 * k + 3] = s4.w;
        atomicAdd(&h[d4.x >> 8], 1u);
        atomicAdd(&h[d4.y >> 8], 1u);
        atomicAdd(&h[d4.z >> 8], 1u);
        atomicAdd(&h[d4.w >> 8], 1u);
    }
    __syncthreads();
    uint v = h[t];
    uint sv = v;                                  // wave-level inclusive scan
#pragma unroll
    for (int off = 1; off < 64; off <<= 1) {
        uint n = __shfl_up(sv, off);
        if (lane >= off) sv += n;
    }
    if (lane == 63) wsum[w] = sv;
    __syncthreads();
    uint wo = 0;
    for (int i = 0; i < w; ++i) wo += wsum[i];
    sv += wo;                                     // inclusive over 512 buckets
    uint ex = sv - v;                             // local exclusive offset
    dirw[(size_t)g * NB + t] = v | (ex << 16);    // coalesced directory store
    __syncthreads();                              // all reads of h done
    h[t] = ex;                                    // bump starts at excl
    __syncthreads();
#pragma unroll
    for (int k = 0; k < EPT; ++k) {
        int b = d[k] >> 8;
        uint slot = atomicAdd(&h[b], 1u);
        vals[slot] = ((uint)s[k] << 8) | (uint)(d[k] & 255);
    }
    __syncthreads();
    uint4* part4 = (uint4*)(part + (size_t)g * CHUNK);
    const uint4* vals4 = (const uint4*)vals;
#pragma unroll
    for (int k = 0; k < EPT / 4; ++k)             // fully coalesced 16B stores
        part4[k * SCT + t] = vals4[k * SCT + t];
}

// ---- Pass 2: searchless run-walk gather -> part2 (bucket-contiguous), ------
// node degrees (native uint bins), dinv, y = dinv*x. 1024 threads.
__global__ void __launch_bounds__(GT) k_gather(
        const uint* __restrict__ part, const uint* __restrict__ dirw,
        const float* __restrict__ x,
        uint* __restrict__ part2, uint* __restrict__ blen,
        float* __restrict__ dinv, float2* __restrict__ y) {
    __shared__ uint ps[NB + 1];     // exclusive prefix of run lengths
    __shared__ uint segoff[NB];     // global offset of each run in part
    __shared__ uint hw[16 * 256];   // wave-private node-bin counters (16 KB)
    __shared__ uint wsum[8];
    int t = threadIdx.x, b = blockIdx.x;
    int lane = t & 63, w = t >> 6;
#pragma unroll
    for (int k = 0; k < 4; ++k) hw[k * GT + t] = 0;
    if (t < NB) {
        uint pd = dirw[(size_t)t * NB + b];       // column read (L2-hot)
        uint len = pd & 0xFFFFu;
        segoff[t] = (uint)t * CHUNK + (pd >> 16);
        uint sv = len;
#pragma unroll
        for (int off = 1; off < 64; off <<= 1) {
            uint n = __shfl_up(sv, off);
            if (lane >= off) sv += n;
        }
        if (lane == 63) wsum[w] = sv;
        ps[t] = sv - len;                         // partial (pre cross-wave)
    }
    __syncthreads();
    if (t < NB) {
        uint wo = 0;
        for (int i = 0; i < w; ++i) wo += wsum[i];
        ps[t] += wo;
    }
    if (t == 0) {
        uint Lt = 0;
#pragma unroll
        for (int i = 0; i < 8; ++i) Lt += wsum[i];
        ps[NB] = Lt;
    }
    __syncthreads();
    uint L = ps[NB];
    uint* o2 = part2 + (size_t)b * CAPB;
    int sub = lane >> 4, l16 = lane & 15;         // 4 runs per wave
#pragma unroll
    for (int pass = 0; pass < 8; ++pass) {        // 16 waves * 4 * 8 = 512 runs
        int r = pass * 64 + w * 4 + sub;
        uint off = segoff[r], base = ps[r], len = ps[r + 1] - base;
        for (uint j = l16; j < len; j += 16) {
            uint pk = part[off + j];
            atomicAdd(&hw[w * 256 + (pk & 255u)], 1u);
            if (base + j < (uint)CAPB) o2[base + j] = pk;   // direct store
        }
    }
    __syncthreads();
    uint Lc = (L > (uint)CAPB) ? (uint)CAPB : L;
    uint Lp = (Lc + 3u) & ~3u;                    // pad to x4 for uint4 readers
    uint i2 = Lc + (uint)t;
    if (i2 < Lp) o2[i2] = SENT;                   // <=3 sentinel pads
    if (t == 0) blen[b] = Lp;
    if (t < 256) {
        uint c = 0;
#pragma unroll
        for (int k = 0; k < 16; ++k) c += hw[k * 256 + t];
        int node = (b << 8) + t;
        float di = rsqrtf(1.0f + (float)c);       // +1 self-loop
        dinv[node] = di;
        float2 xv = ((const float2*)x)[node];
        y[node] = make_float2(di * xv.x, di * xv.y);
    }
}

// ---- Pass 3: layer 1 — uint4 streaming, native int LDS bins + fused MLP ----
__global__ void __launch_bounds__(LT) k_l1(
        const uint* __restrict__ part2, const uint* __restrict__ blen,
        const float2* __restrict__ y, const float* __restrict__ dinv,
        const float* __restrict__ W1, const float* __restrict__ b1,
        const float* __restrict__ W2, float* __restrict__ g2) {
    __shared__ int a0[16 * 256], a1[16 * 256];    // 32 KB, wave-private
    int t = threadIdx.x, b = blockIdx.x, w = t >> 6;
#pragma unroll
    for (int k = 0; k < 4; ++k) { a0[k * LT + t] = 0; a1[k * LT + t] = 0; }
    __syncthreads();
    uint L4 = blen[b] >> 2;
    const uint4* p4 = (const uint4*)(part2 + (size_t)b * CAPB);
    for (uint i = t; i < L4; i += LT) {
        uint4 q = p4[i];
        bool v0 = q.x != SENT, v1 = q.y != SENT, v2 = q.z != SENT, v3 = q.w != SENT;
        float2 y0, y1, y2, y3;                    // issue all gathers first (MLP)
        if (v0) y0 = y[q.x >> 8];
        if (v1) y1 = y[q.y >> 8];
        if (v2) y2 = y[q.z >> 8];
        if (v3) y3 = y[q.w >> 8];
        if (v0) { atomicAdd(&a0[w * 256 + (q.x & 255u)], __float2int_rn(y0.x * S1));
                  atomicAdd(&a1[w * 256 + (q.x & 255u)], __float2int_rn(y0.y * S1)); }
        if (v1) { atomicAdd(&a0[w * 256 + (q.y & 255u)], __float2int_rn(y1.x * S1));
                  atomicAdd(&a1[w * 256 + (q.y & 255u)], __float2int_rn(y1.y * S1)); }
        if (v2) { atomicAdd(&a0[w * 256 + (q.z & 255u)], __float2int_rn(y2.x * S1));
                  atomicAdd(&a1[w * 256 + (q.z & 255u)], __float2int_rn(y2.y * S1)); }
        if (v3) { atomicAdd(&a0[w * 256 + (q.w & 255u)], __float2int_rn(y3.x * S1));
                  atomicAdd(&a1[w * 256 + (q.w & 255u)], __float2int_rn(y3.y * S1)); }
    }
    __syncthreads();
    if (t < 256) {
        int s0 = 0, s1 = 0;
#pragma unroll
        for (int k = 0; k < 16; ++k) { s0 += a0[k * 256 + t]; s1 += a1[k * 256 + t]; }
        int node = (b << 8) + t;
        float di = dinv[node];
        float2 yn = y[node];
        float A0 = di * ((float)s0 * (1.0f / S1) + yn.x);   // + self-loop
        float A1 = di * ((float)s1 * (1.0f / S1) + yn.y);
        float acc = 0.0f;
#pragma unroll
        for (int f = 0; f < F; ++f) {
            float v = fmaf(A0, W1[f], fmaf(A1, W1[F + f], b1[f]));
            acc = fmaf(fmaxf(v, 0.0f), W2[f], acc);
        }
        g2[node] = di * acc;
    }
}

// ---- Pass 4: layer 2 — uint4 streaming, native int LDS bins + sigmoid ------
__global__ void __launch_bounds__(LT) k_l2(
        const uint* __restrict__ part2, const uint* __restrict__ blen,
        const float* __restrict__ g2, const float* __restrict__ dinv,
        const float* __restrict__ b2, float* __restrict__ scores) {
    __shared__ int a[16 * 256];                   // 16 KB, wave-private
    int t = threadIdx.x, b = blockIdx.x, w = t >> 6;
#pragma unroll
    for (int k = 0; k < 4; ++k) a[k * LT + t] = 0;
    __syncthreads();
    uint L4 = blen[b] >> 2;
    const uint4* p4 = (const uint4*)(part2 + (size_t)b * CAPB);
    for (uint i = t; i < L4; i += LT) {
        uint4 q = p4[i];
        uint pk;
#pragma unroll
        for (int k = 0; k < 4; ++k) {
            pk = (k == 0) ? q.x : (k == 1) ? q.y : (k == 2) ? q.z : q.w;
            if (pk != SENT)
                atomicAdd(&a[w * 256 + (pk & 255u)], __float2int_rn(g2[pk >> 8] * S2));
        }
    }
    __syncthreads();
    if (t < 256) {
        int s = 0;
#pragma unroll
        for (int k = 0; k < 16; ++k) s += a[k * 256 + t];
        int node = (b << 8) + t;
        float acc = (float)s * (1.0f / S2);
        float v = fmaf(dinv[node], acc + g2[node], b2[0]);
        scores[node] = 1.0f / (1.0f + expf(-v));
    }
}

// ---- output gather: out[e] = scores[src[e]], 4 edges/thread ----------------
__global__ void k_out(const int* __restrict__ src, const float* __restrict__ scores,
                      float* __restrict__ out) {
    int i = blockIdx.x * blockDim.x + threadIdx.x;
    if (i >= E / 4) return;
    int4 s4 = ((const int4*)src)[i];
    float4 o;
    o.x = scores[s4.x];
    o.y = scores[s4.y];
    o.z = scores[s4.z];
    o.w = scores[s4.w];
    ((float4*)out)[i] = o;
}

extern "C" void kernel_launch(void* const* d_in, const int* in_sizes, int n_in,
                              void* d_out, int out_size, void* d_ws, size_t ws_size,
                              hipStream_t stream) {
    const float* x  = (const float*)d_in[0];   // [N,2]
    const float* W1 = (const float*)d_in[1];   // [2,16]
    const float* b1 = (const float*)d_in[2];   // [16]
    const float* W2 = (const float*)d_in[3];   // [16,1]
    const float* b2 = (const float*)d_in[4];   // [1]
    const int*   ei = (const int*)d_in[5];     // [2,E]
    const int* src = ei;
    const int* dst = ei + E;

    // ws: dirw[512*512 u32] | blen[NB] | dinv[N] | y[N f32x2] | g2[N] |
    //     scores[N] | part2[NB*CAPB u32]   (~22.4 MB)
    uint* dirw    = (uint*)d_ws;
    uint* blen    = dirw + (size_t)NBLK * NB;
    float* dinv   = (float*)(blen + NB);
    float2* y     = (float2*)(dinv + N);
    float* g2     = (float*)(y + N);
    float* scores = g2 + N;
    uint* part2   = (uint*)(scores + N);

    // block-grouped edges (16 MB) live in d_out; dead before k_out writes
    uint* part  = (uint*)d_out;
    float* out  = (float*)d_out;

    k_scatter<<<NBLK,        SCT, 0, stream>>>(src, dst, part, dirw);
    k_gather <<<NB,          GT,  0, stream>>>(part, dirw, x, part2, blen, dinv, y);
    k_l1     <<<NB,          LT,  0, stream>>>(part2, blen, y, dinv, W1, b1, W2, g2);
    k_l2     <<<NB,          LT,  0, stream>>>(part2, blen, g2, dinv, b2, scores);
    k_out    <<<E / 4 / 256, 256, 0, stream>>>(src, scores, out);
}